// Round 17
// baseline (1386.017 us; speedup 1.0000x reference)
//
#include <hip/hip_runtime.h>

#define Bdim 512
#define Tt   256
#define Ii   128
#define Hh   512
#define BM   16     // batch rows per group
#define NGRP 32
#define NSL  8      // column slices (WGs) per group

typedef __attribute__((ext_vector_type(4))) float f32x4;
typedef __attribute__((ext_vector_type(8))) short short8;
typedef __attribute__((ext_vector_type(2))) unsigned long long u64x2;
typedef unsigned long long u64;
typedef unsigned u32;

__device__ __forceinline__ unsigned short f2bf(float f) {
    u32 u = __builtin_bit_cast(u32, f);
    u += 0x7fffu + ((u >> 16) & 1u);   // round-to-nearest-even
    return (unsigned short)(u >> 16);
}

__device__ __forceinline__ short8 pack_bf8(f32x4 lo, f32x4 hi) {
    short8 r;
    r[0] = (short)f2bf(lo[0]); r[1] = (short)f2bf(lo[1]);
    r[2] = (short)f2bf(lo[2]); r[3] = (short)f2bf(lo[3]);
    r[4] = (short)f2bf(hi[0]); r[5] = (short)f2bf(hi[1]);
    r[6] = (short)f2bf(hi[2]); r[7] = (short)f2bf(hi[3]);
    return r;
}

// weight A-fragment: lane holds W[row][k..k+8), K-order: h-cols then x-cols
__device__ __forceinline__ short8 load_wfrag(const float* __restrict__ Whh,
                                             const float* __restrict__ Wih,
                                             int row, int k) {
    const float* p = (k < Hh) ? (Whh + row * Hh + k) : (Wih + row * Ii + (k - Hh));
    f32x4 lo = *(const f32x4*)p;
    f32x4 hi = *(const f32x4*)(p + 4);
    return pack_bf8(lo, hi);
}

__device__ __forceinline__ float sigm(float v)  { return 1.f / (1.f + __expf(-v)); }
__device__ __forceinline__ float tanhf_(float v){ return 1.f - 2.f / (__expf(2.f * v) + 1.f); }

// PROVEN exchange primitives (agent scope / LLC, rounds 4-11)
__device__ __forceinline__ u64 aload(const u64* p) {
    return __hip_atomic_load(p, __ATOMIC_RELAXED, __HIP_MEMORY_SCOPE_AGENT);
}
__device__ __forceinline__ void astore(u64* p, u64 v) {
    __hip_atomic_store(p, v, __ATOMIC_RELAXED, __HIP_MEMORY_SCOPE_AGENT);
}
__device__ __forceinline__ int aload32(const int* p) {
    return __hip_atomic_load(p, __ATOMIC_RELAXED, __HIP_MEMORY_SCOPE_AGENT);
}
__device__ __forceinline__ void astore32(int* p, int v) {
    __hip_atomic_store(p, v, __ATOMIC_RELAXED, __HIP_MEMORY_SCOPE_AGENT);
}

#define MFMA16(A, B, C) __builtin_amdgcn_mfma_f32_16x16x32_bf16((A), (B), (C), 0, 0, 0)

__global__ void init_flags(int* f, int n) {
    int i = blockIdx.x * blockDim.x + threadIdx.x;
    if (i < n) f[i] = -1;
}

// One-time x -> fragment-ordered bf16: xf entry idx = ((g*Tt+t)*4+kt)*64+lane
// holds lane's B-fragment x[g*16+(lane&15)][t][(lane>>4)*8 + kt*32 .. +8) as
// 8 bf16 (16B). One thread per entry.
__global__ void prep_x(const float* __restrict__ x, u64* __restrict__ xf) {
    int idx = blockIdx.x * blockDim.x + threadIdx.x;   // [0, 2^21)
    int lane = idx & 63;
    int kt   = (idx >> 6) & 3;
    int t    = (idx >> 8) & 255;
    int g    = idx >> 16;
    int l15 = lane & 15, cg = lane >> 4;
    const float* xp = x + ((size_t)(g * 16 + l15) * Tt + t) * Ii + cg * 8 + kt * 32;
    short8 v = pack_bf8(*(const f32x4*)xp, *(const f32x4*)(xp + 4));
    *(short8*)(xf + (size_t)idx * 2) = v;
}

// Exchange layout (u64 units), round-6/11 verified:
// F[(buf*NGRP+g)*2048 + kt*128 + l*2 + {0,1}] = consumer lane l's fragment of
// k-tile kt: h[batch=l&15][kt*32+(l>>4)*8 .. +8) as 8 bf16.
// Half H covers k-tiles 8H..8H+7 == slices 4H..4H+3 == flags 16H..16H+15.

#define LOADH(Q, H)                                                             \
    _Pragma("unroll")                                                           \
    for (int s = 0; s < 16; ++s)                                                \
        Q[s] = aload(Frb + ((H) * 8 + (s >> 1)) * 128 + (s & 1));

#define MFMAH(Q, H)                                                             \
    _Pragma("unroll")                                                           \
    for (int k2 = 0; k2 < 8; ++k2) {                                            \
        int kt = (H) * 8 + k2;                                                  \
        u64x2 pp; pp[0] = Q[2 * k2]; pp[1] = Q[2 * k2 + 1];                     \
        short8 bh = __builtin_bit_cast(short8, pp);                             \
        accR  = MFMA16(wR[kt], bh, accR);                                       \
        accZ  = MFMA16(wZ[kt], bh, accZ);                                       \
        accNH = MFMA16(wN[kt], bh, accNH);                                      \
    }

#define POLLH(H, WT)                                                            \
    for (;;) {                                                                  \
        int f_ = aload32(gflags + (H) * 16 + (lane & 15));                      \
        if (__all(f_ >= (WT)) || --budget < 0) break;                           \
    }                                                                           \
    __builtin_amdgcn_sched_barrier(0);

template <bool XB16>
__global__ __launch_bounds__(256, 1)
void gru_persist(const float* __restrict__ x,   const float* __restrict__ Wih,
                 const float* __restrict__ Whh, const float* __restrict__ bih,
                 const float* __restrict__ bhh, const float* __restrict__ Wlin,
                 const float* __restrict__ blin, float* __restrict__ out,
                 u64* __restrict__ F, int* __restrict__ flags,
                 const u64* __restrict__ xf)
{
    const int wg   = blockIdx.x;
    const int tid  = threadIdx.x;
    const int lane = tid & 63;
    const int w    = tid >> 6;          // wave 0..3
    // Keep a group's 8 slices on nearby CUs (perf heuristic only; correctness
    // does not depend on placement — exchange is agent-scope at the LLC).
    const int xcd8 = wg & 7, lg = (wg >> 3) & 3, sl = wg >> 5;
    const int gi  = xcd8 * 4 + lg;      // group 0..31
    const int b0  = gi * BM;
    const int jw  = sl * 64 + w * 16;   // this wave's 16 gate/h columns
    const int l15 = lane & 15;          // batch row within group (D col)
    const int cg  = lane >> 4;          // 4-col chunk / k-half selector
    const int kg8 = cg * 8;
    const int colg = jw + l15;          // gate row this lane holds weights for
    const int kt_w = sl * 2 + (w >> 1); // k-tile this wave's columns fall in
    const int fl   = l15 + 16 * (2 * (w & 1) + (cg >> 1));  // store lane idx

    // biases for lane's 4 gate columns jw + cg*4 + i
    f32x4 brv, bzv, bxnv, bhnv;
#pragma unroll
    for (int i = 0; i < 4; ++i) {
        int c = jw + cg * 4 + i;
        brv[i]  = bih[c] + bhh[c];
        bzv[i]  = bih[Hh + c] + bhh[Hh + c];
        bxnv[i] = bih[2 * Hh + c];
        bhnv[i] = bhh[2 * Hh + c];
    }

    // ---- weight A-fragments, resident for the whole kernel ----
    short8 wR[20], wZ[20], wN[20];
#pragma unroll
    for (int kt = 0; kt < 20; ++kt) {
        int k = kt * 32 + kg8;
        wR[kt] = load_wfrag(Whh, Wih, colg, k);
        wZ[kt] = load_wfrag(Whh, Wih, Hh + colg, k);
        wN[kt] = load_wfrag(Whh, Wih, 2 * Hh + colg, k);
    }

    int* gflags = flags + gi * 32;
    f32x4 hreg = {0.f, 0.f, 0.f, 0.f};  // own (batch=l15, cols jw+cg*4..+4) fp32 carry
    int budget = 1 << 22;               // global spin budget: bug => fast wrong
                                        // answer, never a hang

    // x for t=0
    f32x4 xa[4], xb[4];                 // f32 fallback path
    u64x2 xc[4];                        // bf16 fragment path
    const u64* xgbase = xf + (size_t)gi * Tt * 512 + lane * 2;  // + t*512 + kt*128
    if constexpr (XB16) {
#pragma unroll
        for (int kt = 0; kt < 4; ++kt)
            xc[kt] = *(const u64x2*)(xgbase + 0 * 512 + kt * 128);
    } else {
        const float* xp = x + ((size_t)(b0 + l15) * Tt + 0) * Ii + kg8;
#pragma unroll
        for (int kt = 0; kt < 4; ++kt) {
            xa[kt] = *(const f32x4*)(xp + kt * 32);
            xb[kt] = *(const f32x4*)(xp + kt * 32 + 4);
        }
    }

#pragma unroll 1
    for (int t = 0; t < Tt; ++t) {
        const int wb = t & 1, rb = wb ^ 1;

        f32x4 accR = {0,0,0,0}, accZ = {0,0,0,0}, accNH = {0,0,0,0}, accNX = {0,0,0,0};

        // ---- x-part MFMAs (A=W, B=x^T) ----
#pragma unroll
        for (int kt = 0; kt < 4; ++kt) {
            short8 bxk;
            if constexpr (XB16) bxk = __builtin_bit_cast(short8, xc[kt]);
            else                bxk = pack_bf8(xa[kt], xb[kt]);
            accR  = MFMA16(wR[16 + kt], bxk, accR);
            accZ  = MFMA16(wZ[16 + kt], bxk, accZ);
            accNX = MFMA16(wN[16 + kt], bxk, accNX);
        }

        // x prefetch for t+1: in flight through the whole h-phase
        if (t + 1 < Tt) {
            if constexpr (XB16) {
#pragma unroll
                for (int kt = 0; kt < 4; ++kt)
                    xc[kt] = *(const u64x2*)(xgbase + (size_t)(t + 1) * 512 + kt * 128);
            } else {
                const float* xp = x + ((size_t)(b0 + l15) * Tt + (t + 1)) * Ii + kg8;
#pragma unroll
                for (int kt = 0; kt < 4; ++kt) {
                    xa[kt] = *(const f32x4*)(xp + kt * 32);
                    xb[kt] = *(const f32x4*)(xp + kt * 32 + 4);
                }
            }
        }

        if (t > 0) {
            const int wt = t - 1;
            const u64* Frb = F + (size_t)(rb * NGRP + gi) * 2048 + lane * 2;
            u64 qa[16], qb[16];
            // R11's proven probe point (unpinned, hoistable) + paired half-1 probe
            int f0  = aload32(gflags + (lane & 15));
            int f1p = aload32(gflags + 16 + (lane & 15));
            if (__all(f0 >= wt)) {
                if (__all(f1p >= wt)) {
                    LOADH(qa, 0)
                    LOADH(qb, 1)
                    MFMAH(qa, 0)
                    MFMAH(qb, 1)
                } else {
                    LOADH(qa, 0)
                    POLLH(1, wt)
                    LOADH(qb, 1)
                    MFMAH(qa, 0)
                    MFMAH(qb, 1)
                }
            } else {
                int f1 = aload32(gflags + 16 + (lane & 15));
                if (__all(f1 >= wt)) {
                    LOADH(qb, 1)
                    POLLH(0, wt)
                    LOADH(qa, 0)
                    MFMAH(qb, 1)
                    MFMAH(qa, 0)
                } else {
                    POLLH(0, wt)
                    LOADH(qa, 0)
                    POLLH(1, wt)
                    LOADH(qb, 1)
                    MFMAH(qa, 0)
                    MFMAH(qb, 1)
                }
            }
        }

        // ---- gates + state update (lane: batch=l15, cols jw+cg*4 .. +4) ----
        f32x4 hnew;
#pragma unroll
        for (int i = 0; i < 4; ++i) {
            float r = sigm(accR[i] + brv[i]);
            float z = sigm(accZ[i] + bzv[i]);
            float n = tanhf_(accNX[i] + bxnv[i] + r * (accNH[i] + bhnv[i]));
            hnew[i] = (1.f - z) * n + z * hreg[i];
        }
        hreg = hnew;

        // ---- publish (round-6 verified): pack 4 bf16, pair via shfl_xor(16),
        //      even-chunk lanes store the 16B fragment as 2 u64 atomics ----
        u64 mine = (u64)f2bf(hnew[0])
                 | ((u64)f2bf(hnew[1]) << 16)
                 | ((u64)f2bf(hnew[2]) << 32)
                 | ((u64)f2bf(hnew[3]) << 48);
        u64 part = __shfl_xor(mine, 16);
        if ((cg & 1) == 0) {
            u64* Fw = F + (size_t)(wb * NGRP + gi) * 2048 + (size_t)kt_w * 128 + fl * 2;
            astore(Fw,     mine);
            astore(Fw + 1, part);
        }
        // drain own stores to the coherence point, then post per-wave flag
        asm volatile("s_waitcnt vmcnt(0)" ::: "memory");
        if (lane == 0)
            astore32(gflags + sl * 4 + w, t);
    }

    // ---- final linear: wave 0 of slice-0 WG computes out[b0..b0+15] ----
    if (sl == 0 && w == 0) {
        for (;;) {
            int f = aload32(gflags + (lane & 31));
            if (__all(f >= Tt - 1) || --budget < 0) break;
        }
        __builtin_amdgcn_sched_barrier(0);
        // final state is in buffer (Tt-1)&1 = 1
        const u64* Fr = F + (size_t)(1 * NGRP + gi) * 2048 + lane * 2;
        float sum = 0.f;
#pragma unroll
        for (int kt = 0; kt < 16; ++kt) {
            u64 a = aload(Fr + kt * 128);
            u64 b = aload(Fr + kt * 128 + 1);
            int kbase = kt * 32 + kg8;
#pragma unroll
            for (int j = 0; j < 4; ++j) {
                float fa = __builtin_bit_cast(float,
                              (u32)((a >> (16 * j)) & 0xffffu) << 16);
                float fb = __builtin_bit_cast(float,
                              (u32)((b >> (16 * j)) & 0xffffu) << 16);
                sum += fa * Wlin[kbase + j] + fb * Wlin[kbase + 4 + j];
            }
        }
        sum += __shfl_xor(sum, 16);
        sum += __shfl_xor(sum, 32);
        if (lane < 16) out[b0 + l15] = sum + blin[0];
    }
}

extern "C" void kernel_launch(void* const* d_in, const int* in_sizes, int n_in,
                              void* d_out, int out_size, void* d_ws, size_t ws_size,
                              hipStream_t stream) {
    const float* x    = (const float*)d_in[0];
    const float* Wih  = (const float*)d_in[1];
    const float* Whh  = (const float*)d_in[2];
    const float* bih  = (const float*)d_in[3];
    const float* bhh  = (const float*)d_in[4];
    const float* Wlin = (const float*)d_in[5];
    const float* blin = (const float*)d_in[6];
    float* out  = (float*)d_out;

    const size_t fB  = 2ull * NGRP * 2048 * sizeof(u64);   // 1 MB exchange
    const size_t flB = NGRP * 32 * sizeof(int);            // 4 KB flags
    const size_t xfB = 32ull * Tt * 4 * 64 * 16;           // 32 MB x fragments

    u64* F     = (u64*)d_ws;
    int* flags = (int*)((char*)d_ws + fB);
    u64* xf    = (u64*)((char*)d_ws + fB + flB);

    init_flags<<<4, 256, 0, stream>>>(flags, NGRP * 32);
    if (ws_size >= fB + flB + xfB) {
        prep_x<<<8192, 256, 0, stream>>>(x, xf);
        gru_persist<true><<<256, 256, 0, stream>>>(x, Wih, Whh, bih, bhh,
                                                   Wlin, blin, out, F, flags, xf);
    } else {
        gru_persist<false><<<256, 256, 0, stream>>>(x, Wih, Whh, bih, bhh,
                                                    Wlin, blin, out, F, flags, xf);
    }
}

// Round 18
// 1055.842 us; speedup vs baseline: 1.3127x; 1.3127x over previous
//
#include <hip/hip_runtime.h>

#define Bdim 512
#define Tt   256
#define Ii   128
#define Hh   512
#define BM   16     // batch rows per group
#define NGRP 32
#define NSL  8      // column slices (WGs) per group

typedef __attribute__((ext_vector_type(4))) float f32x4;
typedef __attribute__((ext_vector_type(8))) short short8;
typedef __attribute__((ext_vector_type(2))) unsigned long long u64x2;
typedef unsigned long long u64;
typedef unsigned u32;

__device__ __forceinline__ unsigned short f2bf(float f) {
    u32 u = __builtin_bit_cast(u32, f);
    u += 0x7fffu + ((u >> 16) & 1u);   // round-to-nearest-even
    return (unsigned short)(u >> 16);
}

__device__ __forceinline__ short8 pack_bf8(f32x4 lo, f32x4 hi) {
    short8 r;
    r[0] = (short)f2bf(lo[0]); r[1] = (short)f2bf(lo[1]);
    r[2] = (short)f2bf(lo[2]); r[3] = (short)f2bf(lo[3]);
    r[4] = (short)f2bf(hi[0]); r[5] = (short)f2bf(hi[1]);
    r[6] = (short)f2bf(hi[2]); r[7] = (short)f2bf(hi[3]);
    return r;
}

// weight A-fragment: lane holds W[row][k..k+8), K-order: h-cols then x-cols
__device__ __forceinline__ short8 load_wfrag(const float* __restrict__ Whh,
                                             const float* __restrict__ Wih,
                                             int row, int k) {
    const float* p = (k < Hh) ? (Whh + row * Hh + k) : (Wih + row * Ii + (k - Hh));
    f32x4 lo = *(const f32x4*)p;
    f32x4 hi = *(const f32x4*)(p + 4);
    return pack_bf8(lo, hi);
}

__device__ __forceinline__ float sigm(float v)  { return 1.f / (1.f + __expf(-v)); }
__device__ __forceinline__ float tanhf_(float v){ return 1.f - 2.f / (__expf(2.f * v) + 1.f); }

// PROVEN exchange primitives (agent scope / LLC, rounds 4-11)
__device__ __forceinline__ u64 aload(const u64* p) {
    return __hip_atomic_load(p, __ATOMIC_RELAXED, __HIP_MEMORY_SCOPE_AGENT);
}
__device__ __forceinline__ void astore(u64* p, u64 v) {
    __hip_atomic_store(p, v, __ATOMIC_RELAXED, __HIP_MEMORY_SCOPE_AGENT);
}
__device__ __forceinline__ int aload32(const int* p) {
    return __hip_atomic_load(p, __ATOMIC_RELAXED, __HIP_MEMORY_SCOPE_AGENT);
}
__device__ __forceinline__ void astore32(int* p, int v) {
    __hip_atomic_store(p, v, __ATOMIC_RELAXED, __HIP_MEMORY_SCOPE_AGENT);
}

#define MFMA16(A, B, C) __builtin_amdgcn_mfma_f32_16x16x32_bf16((A), (B), (C), 0, 0, 0)

__global__ void init_flags(int* f, int n) {
    int i = blockIdx.x * blockDim.x + threadIdx.x;
    if (i < n) f[i] = -1;
}

// Exchange layout (u64 units), round-6/11 verified:
// F[(buf*NGRP+g)*2048 + kt*128 + l*2 + {0,1}] = consumer lane l's fragment of
// k-tile kt: h[batch=l&15][kt*32+(l>>4)*8 .. +8) as 8 bf16.
// Half H covers k-tiles 8H..8H+7 == slices 4H..4H+3 == flags 16H..16H+15.

// issue the 16 loads of half H
#define LOADH(Q, H)                                                             \
    _Pragma("unroll")                                                           \
    for (int s = 0; s < 16; ++s)                                                \
        Q[s] = aload(Frb + ((H) * 8 + (s >> 1)) * 128 + (s & 1));

// 24 MFMAs of half H
#define MFMAH(Q, H)                                                             \
    _Pragma("unroll")                                                           \
    for (int k2 = 0; k2 < 8; ++k2) {                                            \
        int kt = (H) * 8 + k2;                                                  \
        u64x2 pp; pp[0] = Q[2 * k2]; pp[1] = Q[2 * k2 + 1];                     \
        short8 bh = __builtin_bit_cast(short8, pp);                             \
        accR  = MFMA16(wR[kt], bh, accR);                                       \
        accZ  = MFMA16(wZ[kt], bh, accZ);                                       \
        accNH = MFMA16(wN[kt], bh, accNH);                                      \
    }

// bounded poll of half H's 16 wave-flags (round-11 verified)
#define POLLH(H, WT)                                                            \
    for (;;) {                                                                  \
        int f_ = aload32(gflags + (H) * 16 + (lane & 15));                      \
        if (__all(f_ >= (WT)) || --budget < 0) break;                           \
    }                                                                           \
    __builtin_amdgcn_sched_barrier(0);

__global__ __launch_bounds__(256, 1)
void gru_persist(const float* __restrict__ x,   const float* __restrict__ Wih,
                 const float* __restrict__ Whh, const float* __restrict__ bih,
                 const float* __restrict__ bhh, const float* __restrict__ Wlin,
                 const float* __restrict__ blin, float* __restrict__ out,
                 u64* __restrict__ F, int* __restrict__ flags)
{
    const int wg   = blockIdx.x;
    const int tid  = threadIdx.x;
    const int lane = tid & 63;
    const int w    = tid >> 6;          // wave 0..3
    // Keep a group's 8 slices on nearby CUs (perf heuristic only; correctness
    // does not depend on placement — exchange is agent-scope at the LLC).
    const int xcd8 = wg & 7, lg = (wg >> 3) & 3, sl = wg >> 5;
    const int gi  = xcd8 * 4 + lg;      // group 0..31
    const int b0  = gi * BM;
    const int jw  = sl * 64 + w * 16;   // this wave's 16 gate/h columns
    const int l15 = lane & 15;          // batch row within group (D col)
    const int cg  = lane >> 4;          // 4-col chunk / k-half selector
    const int kg8 = cg * 8;
    const int colg = jw + l15;          // gate row this lane holds weights for
    const int kt_w = sl * 2 + (w >> 1); // k-tile this wave's columns fall in
    const int fl   = l15 + 16 * (2 * (w & 1) + (cg >> 1));  // store lane idx

    // biases for lane's 4 gate columns jw + cg*4 + i
    f32x4 brv, bzv, bxnv, bhnv;
#pragma unroll
    for (int i = 0; i < 4; ++i) {
        int c = jw + cg * 4 + i;
        brv[i]  = bih[c] + bhh[c];
        bzv[i]  = bih[Hh + c] + bhh[Hh + c];
        bxnv[i] = bih[2 * Hh + c];
        bhnv[i] = bhh[2 * Hh + c];
    }

    // ---- weight A-fragments, resident for the whole kernel ----
    short8 wR[20], wZ[20], wN[20];
#pragma unroll
    for (int kt = 0; kt < 20; ++kt) {
        int k = kt * 32 + kg8;
        wR[kt] = load_wfrag(Whh, Wih, colg, k);
        wZ[kt] = load_wfrag(Whh, Wih, Hh + colg, k);
        wN[kt] = load_wfrag(Whh, Wih, 2 * Hh + colg, k);
    }

    int* gflags = flags + gi * 32;
    f32x4 hreg = {0.f, 0.f, 0.f, 0.f};  // own (batch=l15, cols jw+cg*4..+4) fp32 carry
    int budget = 1 << 22;               // global spin budget: bug => fast wrong
                                        // answer, never a hang

    // x for t=0 (f32 regs, packed transiently at step head)
    f32x4 xa[4], xb[4];
    {
        const float* xp = x + ((size_t)(b0 + l15) * Tt + 0) * Ii + kg8;
#pragma unroll
        for (int kt = 0; kt < 4; ++kt) {
            xa[kt] = *(const f32x4*)(xp + kt * 32);
            xb[kt] = *(const f32x4*)(xp + kt * 32 + 4);
        }
    }

#pragma unroll 1
    for (int t = 0; t < Tt; ++t) {
        const int wb = t & 1, rb = wb ^ 1;

        f32x4 accR = {0,0,0,0}, accZ = {0,0,0,0}, accNH = {0,0,0,0}, accNX = {0,0,0,0};

        // ---- x-part MFMAs (A=W, B=x^T); pack transient ----
#pragma unroll
        for (int kt = 0; kt < 4; ++kt) {
            short8 bxk = pack_bf8(xa[kt], xb[kt]);
            accR  = MFMA16(wR[16 + kt], bxk, accR);
            accZ  = MFMA16(wZ[16 + kt], bxk, accZ);
            accNX = MFMA16(wN[16 + kt], bxk, accNX);
        }

        // x prefetch for t+1: in flight through the whole h-phase
        if (t + 1 < Tt) {
            const float* xp = x + ((size_t)(b0 + l15) * Tt + (t + 1)) * Ii + kg8;
#pragma unroll
            for (int kt = 0; kt < 4; ++kt) {
                xa[kt] = *(const f32x4*)(xp + kt * 32);
                xb[kt] = *(const f32x4*)(xp + kt * 32 + 4);
            }
        }

        if (t > 0) {
            const int wt = t - 1;
            const u64* Frb = F + (size_t)(rb * NGRP + gi) * 2048 + lane * 2;
            u64 qa[16], qb[16];
            // ---- dynamic half-pipelined consumption (R11, measured best):
            //      process whichever half is ready first; overlap the other
            //      half's detect with the first half's loads ----
            int f0 = aload32(gflags + (lane & 15));
            if (__all(f0 >= wt)) {
                LOADH(qa, 0)
                POLLH(1, wt)
                LOADH(qb, 1)
                MFMAH(qa, 0)
                MFMAH(qb, 1)
            } else {
                int f1 = aload32(gflags + 16 + (lane & 15));
                if (__all(f1 >= wt)) {
                    LOADH(qb, 1)
                    POLLH(0, wt)
                    LOADH(qa, 0)
                    MFMAH(qb, 1)
                    MFMAH(qa, 0)
                } else {
                    POLLH(0, wt)
                    LOADH(qa, 0)
                    POLLH(1, wt)
                    LOADH(qb, 1)
                    MFMAH(qa, 0)
                    MFMAH(qb, 1)
                }
            }
        }

        // ---- gates + state update (lane: batch=l15, cols jw+cg*4 .. +4) ----
        f32x4 hnew;
#pragma unroll
        for (int i = 0; i < 4; ++i) {
            float r = sigm(accR[i] + brv[i]);
            float z = sigm(accZ[i] + bzv[i]);
            float n = tanhf_(accNX[i] + bxnv[i] + r * (accNH[i] + bhnv[i]));
            hnew[i] = (1.f - z) * n + z * hreg[i];
        }
        hreg = hnew;

        // ---- publish (round-6 verified): pack 4 bf16, pair via shfl_xor(16),
        //      even-chunk lanes store the 16B fragment as 2 u64 atomics ----
        u64 mine = (u64)f2bf(hnew[0])
                 | ((u64)f2bf(hnew[1]) << 16)
                 | ((u64)f2bf(hnew[2]) << 32)
                 | ((u64)f2bf(hnew[3]) << 48);
        u64 part = __shfl_xor(mine, 16);
        if ((cg & 1) == 0) {
            u64* Fw = F + (size_t)(wb * NGRP + gi) * 2048 + (size_t)kt_w * 128 + fl * 2;
            astore(Fw,     mine);
            astore(Fw + 1, part);
        }
        // drain own stores to the coherence point, then post per-wave flag
        asm volatile("s_waitcnt vmcnt(0)" ::: "memory");
        if (lane == 0)
            astore32(gflags + sl * 4 + w, t);
    }

    // ---- final linear: wave 0 of slice-0 WG computes out[b0..b0+15] ----
    if (sl == 0 && w == 0) {
        for (;;) {
            int f = aload32(gflags + (lane & 31));
            if (__all(f >= Tt - 1) || --budget < 0) break;
        }
        __builtin_amdgcn_sched_barrier(0);
        // final state is in buffer (Tt-1)&1 = 1
        const u64* Fr = F + (size_t)(1 * NGRP + gi) * 2048 + lane * 2;
        float sum = 0.f;
#pragma unroll
        for (int kt = 0; kt < 16; ++kt) {
            u64 a = aload(Fr + kt * 128);
            u64 b = aload(Fr + kt * 128 + 1);
            int kbase = kt * 32 + kg8;
#pragma unroll
            for (int j = 0; j < 4; ++j) {
                float fa = __builtin_bit_cast(float,
                              (u32)((a >> (16 * j)) & 0xffffu) << 16);
                float fb = __builtin_bit_cast(float,
                              (u32)((b >> (16 * j)) & 0xffffu) << 16);
                sum += fa * Wlin[kbase + j] + fb * Wlin[kbase + 4 + j];
            }
        }
        sum += __shfl_xor(sum, 16);
        sum += __shfl_xor(sum, 32);
        if (lane < 16) out[b0 + l15] = sum + blin[0];
    }
}

extern "C" void kernel_launch(void* const* d_in, const int* in_sizes, int n_in,
                              void* d_out, int out_size, void* d_ws, size_t ws_size,
                              hipStream_t stream) {
    const float* x    = (const float*)d_in[0];
    const float* Wih  = (const float*)d_in[1];
    const float* Whh  = (const float*)d_in[2];
    const float* bih  = (const float*)d_in[3];
    const float* bhh  = (const float*)d_in[4];
    const float* Wlin = (const float*)d_in[5];
    const float* blin = (const float*)d_in[6];
    float* out  = (float*)d_out;

    u64* F = (u64*)d_ws;   // 2 bufs * 32 groups * 2048 u64 = 1 MB
    int* flags = (int*)((char*)d_ws + 2ull * NGRP * 2048 * sizeof(u64));

    init_flags<<<4, 256, 0, stream>>>(flags, NGRP * 32);
    gru_persist<<<256, 256, 0, stream>>>(x, Wih, Whh, bih, bhh, Wlin, blin, out,
                                         F, flags);
}